// Round 2
// baseline (439.285 us; speedup 1.0000x reference)
//
#include <hip/hip_runtime.h>

typedef unsigned short u16;
typedef unsigned int   u32;
typedef __attribute__((ext_vector_type(8))) short s16x8;
typedef __attribute__((ext_vector_type(4))) float f32x4;

constexpr int Bc = 2, Sc = 2048, DIMc = 2048, NHc = 16, HDc = 128, Tc = Bc * Sc;
constexpr float LAMBDA_INIT_C = 0.2f;   // 0.8 - 0.6*exp(0)

__device__ __forceinline__ u16 f2bf(float f) {
  union { float f; u32 u; } v; v.f = f;
  u32 r = v.u + 0x7fffu + ((v.u >> 16) & 1u);   // RNE
  return (u16)(r >> 16);
}
__device__ __forceinline__ float bf2f(u16 b) {
  union { u32 u; float f; } v; v.u = ((u32)b) << 16;
  return v.f;
}
__device__ __forceinline__ f32x4 mfma16(s16x8 a, s16x8 b, f32x4 c) {
  return __builtin_amdgcn_mfma_f32_16x16x32_bf16(a, b, c, 0, 0, 0);
}

typedef const __attribute__((address_space(1))) u32 gq32;
typedef __attribute__((address_space(3))) u32 lq32;
__device__ __forceinline__ void cp16(const u16* g, u16* l) {
  __builtin_amdgcn_global_load_lds((gq32*)g, (lq32*)l, 16, 0, 0);
}

// ---------------- fp32 -> bf16 convert: x + 4 contiguous weight tensors --------
__global__ void cvt_all_kernel(const float* __restrict__ x,
                               const float* __restrict__ wq, const float* __restrict__ wk,
                               const float* __restrict__ wv, const float* __restrict__ wo,
                               u16* __restrict__ xb, u16* __restrict__ wb) {
  const int i = blockIdx.x * 256 + threadIdx.x;
  constexpr int NX = Tc * DIMc / 4;       // 2^21 float4
  constexpr int PW = DIMc * DIMc / 4;     // 2^20 float4 per weight
  float4 v; uint2* dst;
  if (i < NX) {
    v = ((const float4*)x)[i];
    dst = ((uint2*)xb) + i;
  } else {
    const int j = i - NX;
    const int which = j >> 20;
    const int jj = j & (PW - 1);
    const float* src = which == 0 ? wq : which == 1 ? wk : which == 2 ? wv : wo;
    v = ((const float4*)src)[jj];
    dst = ((uint2*)wb) + j;
  }
  union { u16 u[4]; uint2 p; } o;
  o.u[0] = f2bf(v.x); o.u[1] = f2bf(v.y); o.u[2] = f2bf(v.z); o.u[3] = f2bf(v.w);
  *dst = o.p;
}

// ================= 256x256x64 8-phase counted-vmcnt GEMM =====================
// C[m][n] = sum_k A[m][k]*B[n][k]; A:[M][2048], B:[N][2048] bf16 row-major.
// MODE 0: bf16 out, N=6144 routed to 3 contiguous [4096][2048] outputs (QKV).
// MODE 1: fp32 out, N=2048.
//
// Geometry (m201 template): 512 thr = 8 waves (2M x 4N), wave tile 128x64,
// acc[8][4] f32x4 (128 VGPR). LDS 128 KiB = 2 bufs x (A 256x64 + B 256x64).
// XOR-swizzle: 16B-slot ^= row&7, via pre-swizzled global source addr and
// swizzled ds_read slot (linear global_load_lds dest) -- both-sides (rule 21).
//
// Per K-tile, 4 phases x 16 MFMA:
//   P0 reads aLo(8)+bc0(4), P1 reads bc1(4), P2 reads aHi(8, overwrites aLo
//   regs) + stages B(kt+2) into CURRENT buf, P3 stages A(kt+2) + vmcnt(8).
// Region-overwrite safety: B regions of cur buf are last ds_read in P1
// (lgkm0 before P1 MFMA, all waves past P1 end-barrier before P2 stage
// issue); A regions last read in P2 -> staged in P3. 2-tiles-ahead staging
// shares buffer parity with the tile being read, hence the post-last-read
// placement. vmcnt(8) at P3 = exactly {B(kt+2),A(kt+2)} may remain in
// flight => A/B(kt+1) resident before kt+1.P0 ds_reads. Never drains to 0
// in the loop. Tail iterations stage wrapped dummies (regions never read
// again) to keep the ledger uniform; one vmcnt(0) after the loop.
template<int MODE>
__global__ __launch_bounds__(512, 2) void gemm8p(const u16* __restrict__ A,
                                                 const u16* __restrict__ Bw,
                                                 u16* __restrict__ Cb,
                                                 float* __restrict__ Cf) {
  constexpr int K = 2048, NT = K / 64;
  constexpr int BUF = 32768;            // u16 per buffer: A 16384 + B 16384
  __shared__ __align__(16) u16 L[2 * BUF];

  const int tid  = threadIdx.x;
  const int lane = tid & 63, w = tid >> 6;
  const int wm = w >> 2, wn = w & 3;
  const int l15 = lane & 15, quad = lane >> 4;

  // XCD swizzle: flat is n-major, so each XCD gets contiguous N-columns
  // (few B panels per XCD; A shared by all, fits L3). nwg % 8 == 0.
  const int mt   = gridDim.y;
  const int nwg  = gridDim.x * mt;
  const int flat = blockIdx.x * mt + blockIdx.y;
  const int swz  = (flat & 7) * (nwg >> 3) + (flat >> 3);
  const int nbase = (swz / mt) * 256;
  const int mbase = (swz % mt) * 256;

  const u16* Ag = A  + (size_t)mbase * K;
  const u16* Bg = Bw + (size_t)nbase * K;

  // staging: thread covers 16B-granules n = l*512+tid (l=0..3) of a 256x64
  // unit; row r=n>>3, LDS slot s=n&7 holds logical k-granule q = s^(r&7).
  u32 soff[4], dlin[4];
#pragma unroll
  for (int l = 0; l < 4; l++) {
    const int n = l * 512 + tid;
    const int r = n >> 3;
    const u32 q = (u32)((n & 7) ^ (r & 7));
    soff[l] = (u32)r * K + q * 8;   // u16 units, global row-major
    dlin[l] = (u32)n * 8;           // u16 units, LDS linear
  }

  auto stA = [&](int kt, int bb) {
#pragma unroll
    for (int l = 0; l < 4; l++)
      cp16(Ag + (size_t)kt * 64 + soff[l], L + bb + dlin[l]);
  };
  auto stB = [&](int kt, int bb) {
#pragma unroll
    for (int l = 0; l < 4; l++)
      cp16(Bg + (size_t)kt * 64 + soff[l], L + bb + 16384 + dlin[l]);
  };

  // ds_read bases; swizzled slot: (q ^ (row&7))<<3, row&7 == l15&7
  const int aB  = (wm * 128 + l15) * 64;
  const int bB  = 16384 + (wn * 64 + l15) * 64;
  const int xq0 = (quad ^ (l15 & 7)) << 3;   // kk=0; kk=1 slot = xq0 ^ 32

  f32x4 acc[8][4];
#pragma unroll
  for (int i = 0; i < 8; i++)
#pragma unroll
    for (int j = 0; j < 4; j++) acc[i][j] = (f32x4){0.f, 0.f, 0.f, 0.f};

  // prologue: B0,A0 -> buf0; B1,A1 -> buf1. vmcnt(8) leaves {B1,A1} in flight.
  stB(0, 0); stA(0, 0); stB(1, BUF); stA(1, BUF);
  asm volatile("s_waitcnt vmcnt(8)" ::: "memory");
  asm volatile("s_barrier" ::: "memory");

  s16x8 a[4][2], b0[2][2], b1[2][2];

  for (int kt = 0; kt < NT; ++kt) {
    const int cb = (kt & 1) * BUF;
    const int tg = (kt + 2 < NT) ? kt + 2 : 0;   // wrapped dummy in tail

    // ---- P0: read aLo(8) + bc0(4); MFMA Q(rows lo, cols 0-1)
#pragma unroll
    for (int i = 0; i < 4; i++) {
      a[i][0] = *(const s16x8*)(L + cb + aB + i * 1024 + xq0);
      a[i][1] = *(const s16x8*)(L + cb + aB + i * 1024 + (xq0 ^ 32));
    }
#pragma unroll
    for (int j = 0; j < 2; j++) {
      b0[j][0] = *(const s16x8*)(L + cb + bB + j * 1024 + xq0);
      b0[j][1] = *(const s16x8*)(L + cb + bB + j * 1024 + (xq0 ^ 32));
    }
    asm volatile("s_barrier" ::: "memory");
    asm volatile("s_waitcnt lgkmcnt(0)" ::: "memory");
    __builtin_amdgcn_sched_barrier(0);
    __builtin_amdgcn_s_setprio(1);
#pragma unroll
    for (int i = 0; i < 4; i++)
#pragma unroll
      for (int j = 0; j < 2; j++) {
        acc[i][j] = mfma16(a[i][0], b0[j][0], acc[i][j]);
        acc[i][j] = mfma16(a[i][1], b0[j][1], acc[i][j]);
      }
    __builtin_amdgcn_s_setprio(0);
    asm volatile("s_barrier" ::: "memory");

    // ---- P1: read bc1(4); MFMA Q(rows lo, cols 2-3)
#pragma unroll
    for (int j = 0; j < 2; j++) {
      b1[j][0] = *(const s16x8*)(L + cb + bB + (j + 2) * 1024 + xq0);
      b1[j][1] = *(const s16x8*)(L + cb + bB + (j + 2) * 1024 + (xq0 ^ 32));
    }
    asm volatile("s_barrier" ::: "memory");
    asm volatile("s_waitcnt lgkmcnt(0)" ::: "memory");
    __builtin_amdgcn_sched_barrier(0);
    __builtin_amdgcn_s_setprio(1);
#pragma unroll
    for (int i = 0; i < 4; i++)
#pragma unroll
      for (int j = 0; j < 2; j++) {
        acc[i][j + 2] = mfma16(a[i][0], b1[j][0], acc[i][j + 2]);
        acc[i][j + 2] = mfma16(a[i][1], b1[j][1], acc[i][j + 2]);
      }
    __builtin_amdgcn_s_setprio(0);
    asm volatile("s_barrier" ::: "memory");

    // ---- P2: read aHi(8, overwrite a[]); stage B(kt+2)->cb; MFMA Q(hi, 2-3)
#pragma unroll
    for (int i = 0; i < 4; i++) {
      a[i][0] = *(const s16x8*)(L + cb + aB + 4096 + i * 1024 + xq0);
      a[i][1] = *(const s16x8*)(L + cb + aB + 4096 + i * 1024 + (xq0 ^ 32));
    }
    stB(tg, cb);
    asm volatile("s_barrier" ::: "memory");
    asm volatile("s_waitcnt lgkmcnt(0)" ::: "memory");
    __builtin_amdgcn_sched_barrier(0);
    __builtin_amdgcn_s_setprio(1);
#pragma unroll
    for (int i = 0; i < 4; i++)
#pragma unroll
      for (int j = 0; j < 2; j++) {
        acc[i + 4][j + 2] = mfma16(a[i][0], b1[j][0], acc[i + 4][j + 2]);
        acc[i + 4][j + 2] = mfma16(a[i][1], b1[j][1], acc[i + 4][j + 2]);
      }
    __builtin_amdgcn_s_setprio(0);
    asm volatile("s_barrier" ::: "memory");

    // ---- P3: stage A(kt+2)->cb; counted vmcnt(8); MFMA Q(hi, 0-1)
    stA(tg, cb);
    asm volatile("s_waitcnt vmcnt(8)" ::: "memory");
    asm volatile("s_barrier" ::: "memory");
    __builtin_amdgcn_sched_barrier(0);
    __builtin_amdgcn_s_setprio(1);
#pragma unroll
    for (int i = 0; i < 4; i++)
#pragma unroll
      for (int j = 0; j < 2; j++) {
        acc[i + 4][j] = mfma16(a[i][0], b0[j][0], acc[i + 4][j]);
        acc[i + 4][j] = mfma16(a[i][1], b0[j][1], acc[i + 4][j]);
      }
    __builtin_amdgcn_s_setprio(0);
    asm volatile("s_barrier" ::: "memory");
  }
  asm volatile("s_waitcnt vmcnt(0)" ::: "memory");   // drain tail dummies

  // ---- epilogue: C write (C/D layout: row = quad*4+r, col = l15)
  if (MODE == 0) {
    const int which = nbase >> 11;
    const int ncol  = nbase & 2047;
    u16* Ob = Cb + (size_t)which * ((size_t)Tc * DIMc);
#pragma unroll
    for (int i = 0; i < 8; i++) {
      const int m0 = mbase + wm * 128 + i * 16 + quad * 4;
#pragma unroll
      for (int j = 0; j < 4; j++) {
        const int n0 = ncol + wn * 64 + j * 16 + l15;
#pragma unroll
        for (int r = 0; r < 4; r++)
          Ob[(size_t)(m0 + r) * 2048 + n0] = f2bf(acc[i][j][r]);
      }
    }
  } else {
#pragma unroll
    for (int i = 0; i < 8; i++) {
      const int m0 = mbase + wm * 128 + i * 16 + quad * 4;
#pragma unroll
      for (int j = 0; j < 4; j++) {
        const int n0 = nbase + wn * 64 + j * 16 + l15;
#pragma unroll
        for (int r = 0; r < 4; r++)
          Cf[(size_t)(m0 + r) * 2048 + n0] = acc[i][j][r];
      }
    }
  }
}

// ---------------- fused prep: rope(q), rope(k), vtrans in one dispatch ----------
__global__ void prep_kernel(const u16* __restrict__ qg, const u16* __restrict__ kg,
                            const u16* __restrict__ vg, const float* __restrict__ fc,
                            u16* __restrict__ qr, u16* __restrict__ kr,
                            u16* __restrict__ vt) {
  __shared__ u16 tile[32][33];
  const int bid = blockIdx.x;
  if (bid < 32768) {
    const bool isq = bid < 16384;
    const u16* xg = isq ? qg : kg;
    u16* outp = isq ? qr : kr;
    const float scale = isq ? 0.125f : 1.0f;  // Q pre-scaled by 1/sqrt(64)
    const int idx = (bid & 16383) * 256 + threadIdx.x;
    const int p = idx & 63;
    const int hh = (idx >> 6) & 15;
    const int tt = idx >> 10;
    const int s = tt & (Sc - 1);
    const int bb = tt >> 11;
    const float c  = fc[(size_t)(s * 64 + p) * 4 + 0] * scale;  // cos
    const float sn = fc[(size_t)(s * 64 + p) * 4 + 2] * scale;  // sin
    const u32 xp = *(const u32*)(xg + (size_t)tt * DIMc + hh * HDc + p * 2);
    const float x0 = bf2f((u16)xp), x1 = bf2f((u16)(xp >> 16));
    const u16 y0 = f2bf(c * x0 - sn * x1);
    const u16 y1 = f2bf(sn * x0 + c * x1);
    *(u32*)(outp + ((size_t)(bb * NHc + hh) * Sc + s) * HDc + p * 2) =
        (u32)y0 | ((u32)y1 << 16);
  } else {
    const int vb = bid - 32768;
    const int bh = vb >> 8;
    const int bb = bh >> 4, hh = bh & 15;
    const int rem = vb & 255;
    const int s0 = (rem & 63) * 32, d0 = (rem >> 6) * 32;
    const int tx = threadIdx.x & 31, ty = threadIdx.x >> 5;
#pragma unroll
    for (int pp = 0; pp < 4; pp++) {
      const int s = s0 + ty + pp * 8;
      tile[ty + pp * 8][tx] = vg[(size_t)(bb * Sc + s) * DIMc + hh * HDc + d0 + tx];
    }
    __syncthreads();
#pragma unroll
    for (int pp = 0; pp < 4; pp++) {
      const int d = d0 + ty + pp * 8;
      vt[((size_t)bh * HDc + d) * Sc + s0 + tx] = tile[tx][ty + pp * 8];
    }
  }
}

// ---------------- fused causal diff-attention -> permuted Y ----------------
// Balanced pairing: block j handles 64-row q-tiles j and 31-j; 64-key chunks
// (two independent 32-key subs per barrier). K rows are PERMUTED at staging
// (per-lane global source addr; LDS dest stays linear) with
// m(s) = (s&3) + ((s>>2)&3)*8 + ((s>>4)<<2), and QK^T is computed transposed
// (A=K, B=Q) so the score C-layout keys at lane (quad,l15) are exactly keys
// quad*8+j -- identical to the PV A-fragment layout and VB's key order. The
// score transpose through LDS disappears; P packs in-register after exp.
__global__ __launch_bounds__(256, 2) void diff_attn_kernel(
    const u16* __restrict__ qr, const u16* __restrict__ kr, const u16* __restrict__ vt,
    const float* __restrict__ lq1, const float* __restrict__ lk1,
    const float* __restrict__ lq2, const float* __restrict__ lk2,
    const float* __restrict__ subw, u16* __restrict__ Y) {
  __shared__ u16 KB[2][8192];   // [buf][hh*512 + dblk*32 + slot][8]
  __shared__ u16 VB[2][8192];   // [buf][hh*512 + keyq*128 + d][8]

  const int h = blockIdx.y, b = blockIdx.z, jb = blockIdx.x;
  const int bh = b * NHc + h;
  const int tid = threadIdx.x;
  const int w = tid >> 6, lane = tid & 63;
  const int l15 = lane & 15, quad = lane >> 4;

  const u16* krb = kr + (size_t)bh * Sc * HDc;
  const u16* vtb = vt + (size_t)bh * HDc * Sc;

  float lp1 = lq1[lane] * lk1[lane];
  float lp2 = lq2[lane] * lk2[lane];
#pragma unroll
  for (int m = 32; m; m >>= 1) { lp1 += __shfl_xor(lp1, m); lp2 += __shfl_xor(lp2, m); }
  const float lam = __expf(lp1) - __expf(lp2) + LAMBDA_INIT_C;

  float wsub[8];
#pragma unroll
  for (int dn = 0; dn < 8; dn++) wsub[dn] = subw[dn * 16 + l15];

  // staging address precompute
  size_t offK[4], offV[4];
  int dstO[4];
#pragma unroll
  for (int oo = 0; oo < 4; oo++) {
    const int n = w * 256 + oo * 64 + lane;
    const int s = n & 31, dblk = (n >> 5) & 15, sub = n >> 9;
    const int mkey = (s & 3) + ((s >> 2) & 3) * 8 + ((s >> 4) << 2);  // key permutation
    offK[oo] = (size_t)(sub * 32 + mkey) * HDc + dblk * 8;
    offV[oo] = (size_t)(n & 127) * Sc + (sub * 32 + ((n >> 7) & 3) * 8);
    dstO[oo] = n * 8;
  }

  for (int ph = 0; ph < 2; ph++) {
    const int t = ph ? (31 - jb) : jb;
    const int rowbase = t * 64 + w * 16;
    const int nc = t + 1;   // 64-key chunks

    const u16* qp = qr + ((size_t)bh * Sc + rowbase + l15) * HDc + quad * 8;
    s16x8 qa[2][2];
    qa[0][0] = *(const s16x8*)(qp);
    qa[0][1] = *(const s16x8*)(qp + 32);
    qa[1][0] = *(const s16x8*)(qp + 64);
    qa[1][1] = *(const s16x8*)(qp + 96);

    f32x4 o[2][8];
#pragma unroll
    for (int st = 0; st < 2; st++)
#pragma unroll
      for (int dn = 0; dn < 8; dn++) o[st][dn] = (f32x4){0.f, 0.f, 0.f, 0.f};
    float lpart[2] = { 0.f, 0.f };

    __syncthreads();  // protect buffers from previous phase's readers
#pragma unroll
    for (int oo = 0; oo < 4; oo++) cp16(krb + offK[oo], KB[0] + dstO[oo]);
#pragma unroll
    for (int oo = 0; oo < 4; oo++) cp16(vtb + offV[oo], VB[0] + dstO[oo]);

    for (int c = 0; c < nc; c++) {
      __syncthreads();
      if (c + 1 < nc) {
        const int kb1 = (c + 1) * 64;
        u16* Kn = KB[(c + 1) & 1];
        u16* Vn = VB[(c + 1) & 1];
#pragma unroll
        for (int oo = 0; oo < 4; oo++) cp16(krb + (size_t)kb1 * HDc + offK[oo], Kn + dstO[oo]);
#pragma unroll
        for (int oo = 0; oo < 4; oo++) cp16(vtb + offV[oo] + kb1, Vn + dstO[oo]);
      }
      const u16* Kb = KB[c & 1];
      const u16* Vb = VB[c & 1];
      const int kb = c * 64;
      const bool diag = (c == nc - 1);

#pragma unroll
      for (int sub = 0; sub < 2; sub++) {
        if (diag && sub == 1 && w < 2) continue;  // fully-masked sub, wave-uniform skip

        // QK^T transposed: A=K (permuted rows), B=Q
        f32x4 sc[2][2];
#pragma unroll
        for (int st = 0; st < 2; st++)
#pragma unroll
          for (int kt = 0; kt < 2; kt++) sc[st][kt] = (f32x4){0.f, 0.f, 0.f, 0.f};
#pragma unroll
        for (int st = 0; st < 2; st++)
#pragma unroll
          for (int kh = 0; kh < 2; kh++) {
            const int base = sub * 512 + (st * 8 + kh * 4 + quad) * 32;
#pragma unroll
            for (int kt = 0; kt < 2; kt++) {
              const s16x8 kf = *(const s16x8*)(Kb + (size_t)(base + kt * 16 + l15) * 8);
              sc[st][kt] = mfma16(kf, qa[st][kh], sc[st][kt]);
            }
          }

        // in-lane exp + mask + partial-l + pack (keys at this lane = quad*8+j)
        s16x8 pa[2];
#pragma unroll
        for (int st = 0; st < 2; st++) {
          float p[8];
#pragma unroll
          for (int kt = 0; kt < 2; kt++)
#pragma unroll
            for (int r = 0; r < 4; r++) p[kt * 4 + r] = __expf(sc[st][kt][r]);
          if (diag) {
            const int qrow = rowbase + l15;
            const int kb0 = kb + sub * 32 + quad * 8;
#pragma unroll
            for (int j8 = 0; j8 < 8; j8++)
              if (kb0 + j8 > qrow) p[j8] = 0.f;
          }
          float sm = 0.f;
#pragma unroll
          for (int j8 = 0; j8 < 8; j8++) sm += p[j8];
          lpart[st] += sm;
          union { u16 us[8]; s16x8 vv; } pk;
#pragma unroll
          for (int j8 = 0; j8 < 8; j8++) pk.us[j8] = f2bf(p[j8]);
          pa[st] = pk.vv;
        }

        // PV
#pragma unroll
        for (int dn = 0; dn < 8; dn++) {
          const s16x8 vf =
              *(const s16x8*)(Vb + (size_t)(sub * 512 + quad * 128 + dn * 16 + l15) * 8);
          o[0][dn] = mfma16(pa[0], vf, o[0][dn]);
          o[1][dn] = mfma16(pa[1], vf, o[1][dn]);
        }
      }
    }

    // epilogue: reduce l partials, combine streams, RMSNorm(128), *0.8, write
    float lL0 = lpart[0], lL1 = lpart[1];
    lL0 += __shfl_xor(lL0, 16); lL0 += __shfl_xor(lL0, 32);
    lL1 += __shfl_xor(lL1, 16); lL1 += __shfl_xor(lL1, 32);
    const float inv1 = 1.f / lL0;
    const float inv2 = lam / lL1;
    float i1C[4], i2C[4];
#pragma unroll
    for (int r = 0; r < 4; r++) {
      i1C[r] = __shfl(inv1, quad * 4 + r, 16);
      i2C[r] = __shfl(inv2, quad * 4 + r, 16);
    }
    float yv[8][4], ss[4] = { 0.f, 0.f, 0.f, 0.f };
#pragma unroll
    for (int dn = 0; dn < 8; dn++)
#pragma unroll
      for (int r = 0; r < 4; r++) {
        const float y = o[0][dn][r] * i1C[r] - o[1][dn][r] * i2C[r];
        yv[dn][r] = y;
        ss[r] += y * y;
      }
#pragma unroll
    for (int r = 0; r < 4; r++) {
#pragma unroll
      for (int mm = 1; mm < 16; mm <<= 1) ss[r] += __shfl_xor(ss[r], mm);
    }
    float scl[4];
#pragma unroll
    for (int r = 0; r < 4; r++) scl[r] = rsqrtf(ss[r] * (1.f / 128.f) + 1e-5f) * 0.8f;

    u16* yrow = Y + ((size_t)(b * Sc + h * 128 + t * 4 + w)) * 2048;
#pragma unroll
    for (int dn = 0; dn < 8; dn++)
#pragma unroll
      for (int r = 0; r < 4; r++)
        yrow[(quad * 4 + r) * 128 + dn * 16 + l15] = f2bf(yv[dn][r] * scl[r] * wsub[dn]);
  }
}

// ---------------- host launcher ----------------
extern "C" void kernel_launch(void* const* d_in, const int* in_sizes, int n_in,
                              void* d_out, int out_size, void* d_ws, size_t ws_size,
                              hipStream_t stream) {
  const float* x    = (const float*)d_in[0];
  const float* fc   = (const float*)d_in[1];
  const float* wq   = (const float*)d_in[2];
  const float* wk   = (const float*)d_in[3];
  const float* wv   = (const float*)d_in[4];
  const float* wo   = (const float*)d_in[5];
  const float* lq1  = (const float*)d_in[6];
  const float* lk1  = (const float*)d_in[7];
  const float* lq2  = (const float*)d_in[8];
  const float* lk2  = (const float*)d_in[9];
  const float* subw = (const float*)d_in[10];
  float* out = (float*)d_out;

  char* ws = (char*)d_ws;
  constexpr size_t SZ_X  = (size_t)Tc * DIMc * 2;        // 16 MB
  constexpr size_t SZ_W  = (size_t)DIMc * DIMc * 2;      // 8 MB
  constexpr size_t SZ_T  = (size_t)Tc * DIMc * 2;        // 16 MB
  u16* xb  = (u16*)(ws);
  u16* wqb = (u16*)(ws + SZ_X);                          // wq,wk,wv,wo contiguous
  u16* wob = (u16*)(ws + SZ_X + 3 * SZ_W);
  u16* qg  = (u16*)(ws + SZ_X + 4 * SZ_W);               // qg,kg,vg contiguous
  u16* kg  = (u16*)(ws + SZ_X + 4 * SZ_W + SZ_T);
  u16* vg  = (u16*)(ws + SZ_X + 4 * SZ_W + 2 * SZ_T);
  u16* qr  = (u16*)(ws + SZ_X + 4 * SZ_W + 3 * SZ_T);
  u16* kr  = (u16*)(ws + SZ_X + 4 * SZ_W + 4 * SZ_T);
  u16* vt  = (u16*)(ws + SZ_X + 4 * SZ_W + 5 * SZ_T);
  u16* Y   = (u16*)(ws + SZ_X + 4 * SZ_W + 6 * SZ_T);

  // 1) fp32 -> bf16 (one dispatch: x + 4 weights)
  cvt_all_kernel<<<(Tc * DIMc / 4 + 4 * DIMc * DIMc / 4) / 256, 256, 0, stream>>>(
      x, wq, wk, wv, wo, xb, wqb);

  // 2) merged QKV projection GEMM: A=xb [4096][2048], B=wqb.. [6144][2048]
  //    grid 24x16 = 384 blocks (256x256 tiles)
  gemm8p<0><<<dim3(DIMc * 3 / 256, Tc / 256), 512, 0, stream>>>(
      xb, wqb, qg, nullptr);

  // 3) fused prep: rope(q, *0.125) + rope(k) + vtrans (one dispatch)
  prep_kernel<<<16384 + 16384 + 8192, 256, 0, stream>>>(qg, kg, vg, fc, qr, kr, vt);

  // 4) fused causal differential attention -> permuted Y
  diff_attn_kernel<<<dim3(16, NHc, Bc), 256, 0, stream>>>(
      qr, kr, vt, lq1, lk1, lq2, lk2, subw, Y);

  // 5) output GEMM (fp32 out): grid 8x16 = 128 blocks (256x256 tiles)
  gemm8p<1><<<dim3(DIMc / 256, Tc / 256), 512, 0, stream>>>(
      Y, wob, nullptr, out);
}

// Round 3
// 416.831 us; speedup vs baseline: 1.0539x; 1.0539x over previous
//
#include <hip/hip_runtime.h>

typedef unsigned short u16;
typedef unsigned int   u32;
typedef __attribute__((ext_vector_type(8))) short s16x8;
typedef __attribute__((ext_vector_type(4))) float f32x4;

constexpr int Bc = 2, Sc = 2048, DIMc = 2048, NHc = 16, HDc = 128, Tc = Bc * Sc;
constexpr float LAMBDA_INIT_C = 0.2f;   // 0.8 - 0.6*exp(0)

__device__ __forceinline__ u16 f2bf(float f) {
  union { float f; u32 u; } v; v.f = f;
  u32 r = v.u + 0x7fffu + ((v.u >> 16) & 1u);   // RNE
  return (u16)(r >> 16);
}
__device__ __forceinline__ float bf2f(u16 b) {
  union { u32 u; float f; } v; v.u = ((u32)b) << 16;
  return v.f;
}
__device__ __forceinline__ f32x4 mfma16(s16x8 a, s16x8 b, f32x4 c) {
  return __builtin_amdgcn_mfma_f32_16x16x32_bf16(a, b, c, 0, 0, 0);
}

typedef const __attribute__((address_space(1))) u32 gq32;
typedef __attribute__((address_space(3))) u32 lq32;
__device__ __forceinline__ void cp16(const u16* g, u16* l) {
  __builtin_amdgcn_global_load_lds((gq32*)g, (lq32*)l, 16, 0, 0);
}

#define BAR()    asm volatile("s_barrier" ::: "memory")
#define LGKM0()  asm volatile("s_waitcnt lgkmcnt(0)" ::: "memory")
#define VMC(n)   asm volatile("s_waitcnt vmcnt(" #n ")" ::: "memory")

// ---------------- fp32 -> bf16 convert: x + 4 contiguous weight tensors --------
__global__ void cvt_all_kernel(const float* __restrict__ x,
                               const float* __restrict__ wq, const float* __restrict__ wk,
                               const float* __restrict__ wv, const float* __restrict__ wo,
                               u16* __restrict__ xb, u16* __restrict__ wb) {
  const int i = blockIdx.x * 256 + threadIdx.x;
  constexpr int NX = Tc * DIMc / 4;       // 2^21 float4
  constexpr int PW = DIMc * DIMc / 4;     // 2^20 float4 per weight
  float4 v; uint2* dst;
  if (i < NX) {
    v = ((const float4*)x)[i];
    dst = ((uint2*)xb) + i;
  } else {
    const int j = i - NX;
    const int which = j >> 20;
    const int jj = j & (PW - 1);
    const float* src = which == 0 ? wq : which == 1 ? wk : which == 2 ? wv : wo;
    v = ((const float4*)src)[jj];
    dst = ((uint2*)wb) + j;
  }
  union { u16 u[4]; uint2 p; } o;
  o.u[0] = f2bf(v.x); o.u[1] = f2bf(v.y); o.u[2] = f2bf(v.z); o.u[3] = f2bf(v.w);
  *dst = o.p;
}

// ================= BMx256x64 8-phase counted-vmcnt GEMM ======================
// C[m][n] = sum_k A[m][k]*B[n][k]; A:[M][2048], B:[N][2048] bf16 row-major.
// MODE 0 (BM=256): bf16 out, N=6144 routed to 3 [4096][2048] outputs (QKV).
// MODE 1 (BM=128): fp32 out, N=2048 (grid 8x32 = 256 blocks = 1/CU exact).
//
// 512 thr = 8 waves (2M x 4N), wave tile (BM/2)x64, acc[AF][4], AF=BM/32.
// LDS = 2 bufs x (A BMx64 + B 256x64) bf16, XOR-swizzle 16B-slot ^= row&7
// (pre-swizzled global source + swizzled ds_read, linear gload_lds dest).
//
// Phases split per-kk for BALANCED LDS traffic (8/4/8/4 reads, vs 12/4/8/0
// in the previous rev whose bursty P0 made LDS the per-phase critical path):
//   P0: read b[0..3]@k0 + aLo@k0; stage A(kt+1)->other buf; MFMA C_lo x k0
//   P1: read aHi@k0;                                         MFMA C_hi x k0
//   P2: read b[0..3]@k1 + aLo@k1 (overwrite regs);           MFMA C_lo x k1
//   P3: read aHi@k1; stage B(kt+2)->cur buf; vmcnt(4);       MFMA C_hi x k1
// Region safety: other-buf A last read (kt-1).P3 -> stage at kt.P0; cur-buf
// B last read kt.P2 -> stage at kt.P3. vmcnt(4) at P3 pre-barrier: only the
// just-issued B(kt+2) [4 loads] may remain outstanding => A(kt+1) (issued
// kt.P0, 3 phases earlier) and B(kt+1) (issued (kt-1).P3) complete before
// any wave crosses into (kt+1).P0's ds_reads. Never drains to 0 in-loop.
// Tail stages wrapped kt=0 dummies into never-again-read regions.
template<int MODE, int BM>
__global__ __launch_bounds__(512, 2) void gemm8p(const u16* __restrict__ A,
                                                 const u16* __restrict__ Bw,
                                                 u16* __restrict__ Cb,
                                                 float* __restrict__ Cf) {
  constexpr int K = 2048, NT = K / 64;
  constexpr int AF  = BM / 32;           // A m-frags per wave
  constexpr int AU  = BM * 64;           // u16 per A unit
  constexpr int ALD = BM / 64;           // A stage loads per thread
  constexpr int BUF = AU + 16384;        // u16 per buffer (A + B 256x64)
  __shared__ __align__(16) u16 L[2 * BUF];

  const int tid  = threadIdx.x;
  const int lane = tid & 63, w = tid >> 6;
  const int wm = w >> 2, wn = w & 3;
  const int l15 = lane & 15, quad = lane >> 4;

  // XCD swizzle (n-major flat: each XCD gets contiguous N-columns; B panels
  // per XCD few, A shared via L3). nwg % 8 == 0 for both launches.
  const int mt   = gridDim.y;
  const int nwg  = gridDim.x * mt;
  const int flat = blockIdx.x * mt + blockIdx.y;
  const int swz  = (flat & 7) * (nwg >> 3) + (flat >> 3);
  const int nbase = (swz / mt) * 256;
  const int mbase = (swz % mt) * BM;

  const u16* Ag = A  + (size_t)mbase * K;
  const u16* Bg = Bw + (size_t)nbase * K;

  // staging: 16B-granule n = l*512+tid; row r=n>>3, LDS slot s=n&7 holds
  // logical k-granule q = s^(r&7)  (inverse-swizzled global source).
  u32 soffA[ALD], dlinA[ALD], soffB[4], dlinB[4];
#pragma unroll
  for (int l = 0; l < ALD; l++) {
    const int n = l * 512 + tid;
    const int r = n >> 3;
    const u32 q = (u32)((n & 7) ^ (r & 7));
    soffA[l] = (u32)r * K + q * 8;
    dlinA[l] = (u32)n * 8;
  }
#pragma unroll
  for (int l = 0; l < 4; l++) {
    const int n = l * 512 + tid;
    const int r = n >> 3;
    const u32 q = (u32)((n & 7) ^ (r & 7));
    soffB[l] = (u32)r * K + q * 8;
    dlinB[l] = (u32)(AU + n * 8);
  }

  auto stA = [&](int kt, int bb) {
#pragma unroll
    for (int l = 0; l < ALD; l++)
      cp16(Ag + (size_t)kt * 64 + soffA[l], L + bb + dlinA[l]);
  };
  auto stB = [&](int kt, int bb) {
#pragma unroll
    for (int l = 0; l < 4; l++)
      cp16(Bg + (size_t)kt * 64 + soffB[l], L + bb + dlinB[l]);
  };

  // ds_read bases; swizzled slot (q ^ (row&7))<<3, row&7 == l15&7
  const int aB  = (wm * (BM / 2) + l15) * 64;
  const int bB  = AU + (wn * 64 + l15) * 64;
  const int xq0 = (quad ^ (l15 & 7)) << 3;   // kk=0; kk=1 slot = xq0 ^ 32

  f32x4 acc[AF][4];
#pragma unroll
  for (int i = 0; i < AF; i++)
#pragma unroll
    for (int j = 0; j < 4; j++) acc[i][j] = (f32x4){0.f, 0.f, 0.f, 0.f};

  // prologue: B0,A0 -> buf0; B1 -> buf1. vmcnt(4) leaves B1 in flight.
  stB(0, 0); stA(0, 0); stB(1, BUF);
  VMC(4);
  BAR();

  s16x8 a[AF], b[4];

  for (int kt = 0; kt < NT; ++kt) {
    const int cb = (kt & 1) * BUF;
    const int nb = BUF - cb;
    const int tgA = (kt + 1 < NT) ? kt + 1 : 0;   // wrapped dummy in tail
    const int tgB = (kt + 2 < NT) ? kt + 2 : 0;

    // ---- P0: b@k0 (4) + aLo@k0 (AF/2); stage A(kt+1)->nb; MFMA lo x k0
#pragma unroll
    for (int j = 0; j < 4; j++)
      b[j] = *(const s16x8*)(L + cb + bB + j * 1024 + xq0);
#pragma unroll
    for (int i = 0; i < AF / 2; i++)
      a[i] = *(const s16x8*)(L + cb + aB + i * 1024 + xq0);
    stA(tgA, nb);
    BAR(); LGKM0();
    __builtin_amdgcn_sched_barrier(0);
    __builtin_amdgcn_s_setprio(1);
#pragma unroll
    for (int i = 0; i < AF / 2; i++)
#pragma unroll
      for (int j = 0; j < 4; j++) acc[i][j] = mfma16(a[i], b[j], acc[i][j]);
    __builtin_amdgcn_s_setprio(0);
    BAR();

    // ---- P1: aHi@k0 (AF/2); MFMA hi x k0
#pragma unroll
    for (int i = AF / 2; i < AF; i++)
      a[i] = *(const s16x8*)(L + cb + aB + i * 1024 + xq0);
    BAR(); LGKM0();
    __builtin_amdgcn_sched_barrier(0);
    __builtin_amdgcn_s_setprio(1);
#pragma unroll
    for (int i = AF / 2; i < AF; i++)
#pragma unroll
      for (int j = 0; j < 4; j++) acc[i][j] = mfma16(a[i], b[j], acc[i][j]);
    __builtin_amdgcn_s_setprio(0);
    BAR();

    // ---- P2: b@k1 (4) + aLo@k1 (AF/2, overwrite); MFMA lo x k1
#pragma unroll
    for (int j = 0; j < 4; j++)
      b[j] = *(const s16x8*)(L + cb + bB + j * 1024 + (xq0 ^ 32));
#pragma unroll
    for (int i = 0; i < AF / 2; i++)
      a[i] = *(const s16x8*)(L + cb + aB + i * 1024 + (xq0 ^ 32));
    BAR(); LGKM0();
    __builtin_amdgcn_sched_barrier(0);
    __builtin_amdgcn_s_setprio(1);
#pragma unroll
    for (int i = 0; i < AF / 2; i++)
#pragma unroll
      for (int j = 0; j < 4; j++) acc[i][j] = mfma16(a[i], b[j], acc[i][j]);
    __builtin_amdgcn_s_setprio(0);
    BAR();

    // ---- P3: aHi@k1 (AF/2); stage B(kt+2)->cb; vmcnt(4); MFMA hi x k1
#pragma unroll
    for (int i = AF / 2; i < AF; i++)
      a[i] = *(const s16x8*)(L + cb + aB + i * 1024 + (xq0 ^ 32));
    stB(tgB, cb);
    VMC(4);
    BAR(); LGKM0();
    __builtin_amdgcn_sched_barrier(0);
    __builtin_amdgcn_s_setprio(1);
#pragma unroll
    for (int i = AF / 2; i < AF; i++)
#pragma unroll
      for (int j = 0; j < 4; j++) acc[i][j] = mfma16(a[i], b[j], acc[i][j]);
    __builtin_amdgcn_s_setprio(0);
    BAR();
  }
  asm volatile("s_waitcnt vmcnt(0)" ::: "memory");   // drain tail dummies

  // ---- epilogue: C write (C/D layout: row = quad*4+r, col = l15)
  if (MODE == 0) {
    const int which = nbase >> 11;
    const int ncol  = nbase & 2047;
    u16* Ob = Cb + (size_t)which * ((size_t)Tc * DIMc);
#pragma unroll
    for (int i = 0; i < AF; i++) {
      const int m0 = mbase + wm * (BM / 2) + i * 16 + quad * 4;
#pragma unroll
      for (int j = 0; j < 4; j++) {
        const int n0 = ncol + wn * 64 + j * 16 + l15;
#pragma unroll
        for (int r = 0; r < 4; r++)
          Ob[(size_t)(m0 + r) * 2048 + n0] = f2bf(acc[i][j][r]);
      }
    }
  } else {
#pragma unroll
    for (int i = 0; i < AF; i++) {
      const int m0 = mbase + wm * (BM / 2) + i * 16 + quad * 4;
#pragma unroll
      for (int j = 0; j < 4; j++) {
        const int n0 = nbase + wn * 64 + j * 16 + l15;
#pragma unroll
        for (int r = 0; r < 4; r++)
          Cf[(size_t)(m0 + r) * 2048 + n0] = acc[i][j][r];
      }
    }
  }
}

// ---------------- fused prep: rope(q), rope(k), vtrans in one dispatch ----------
__global__ void prep_kernel(const u16* __restrict__ qg, const u16* __restrict__ kg,
                            const u16* __restrict__ vg, const float* __restrict__ fc,
                            u16* __restrict__ qr, u16* __restrict__ kr,
                            u16* __restrict__ vt) {
  __shared__ u16 tile[32][33];
  const int bid = blockIdx.x;
  if (bid < 32768) {
    const bool isq = bid < 16384;
    const u16* xg = isq ? qg : kg;
    u16* outp = isq ? qr : kr;
    const float scale = isq ? 0.125f : 1.0f;  // Q pre-scaled by 1/sqrt(64)
    const int idx = (bid & 16383) * 256 + threadIdx.x;
    const int p = idx & 63;
    const int hh = (idx >> 6) & 15;
    const int tt = idx >> 10;
    const int s = tt & (Sc - 1);
    const int bb = tt >> 11;
    const float c  = fc[(size_t)(s * 64 + p) * 4 + 0] * scale;  // cos
    const float sn = fc[(size_t)(s * 64 + p) * 4 + 2] * scale;  // sin
    const u32 xp = *(const u32*)(xg + (size_t)tt * DIMc + hh * HDc + p * 2);
    const float x0 = bf2f((u16)xp), x1 = bf2f((u16)(xp >> 16));
    const u16 y0 = f2bf(c * x0 - sn * x1);
    const u16 y1 = f2bf(sn * x0 + c * x1);
    *(u32*)(outp + ((size_t)(bb * NHc + hh) * Sc + s) * HDc + p * 2) =
        (u32)y0 | ((u32)y1 << 16);
  } else {
    const int vb = bid - 32768;
    const int bh = vb >> 8;
    const int bb = bh >> 4, hh = bh & 15;
    const int rem = vb & 255;
    const int s0 = (rem & 63) * 32, d0 = (rem >> 6) * 32;
    const int tx = threadIdx.x & 31, ty = threadIdx.x >> 5;
#pragma unroll
    for (int pp = 0; pp < 4; pp++) {
      const int s = s0 + ty + pp * 8;
      tile[ty + pp * 8][tx] = vg[(size_t)(bb * Sc + s) * DIMc + hh * HDc + d0 + tx];
    }
    __syncthreads();
#pragma unroll
    for (int pp = 0; pp < 4; pp++) {
      const int d = d0 + ty + pp * 8;
      vt[((size_t)bh * HDc + d) * Sc + s0 + tx] = tile[tx][ty + pp * 8];
    }
  }
}

// ---------------- fused causal diff-attention -> permuted Y ----------------
// Balanced pairing: block j handles 64-row q-tiles j and 31-j; 64-key chunks
// (two independent 32-key subs per barrier). K rows are PERMUTED at staging
// (per-lane global source addr; LDS dest stays linear) with
// m(s) = (s&3) + ((s>>2)&3)*8 + ((s>>4)<<2), and QK^T is computed transposed
// (A=K, B=Q) so the score C-layout keys at lane (quad,l15) are exactly keys
// quad*8+j -- identical to the PV A-fragment layout and VB's key order. The
// score transpose through LDS disappears; P packs in-register after exp.
__global__ __launch_bounds__(256, 2) void diff_attn_kernel(
    const u16* __restrict__ qr, const u16* __restrict__ kr, const u16* __restrict__ vt,
    const float* __restrict__ lq1, const float* __restrict__ lk1,
    const float* __restrict__ lq2, const float* __restrict__ lk2,
    const float* __restrict__ subw, u16* __restrict__ Y) {
  __shared__ u16 KB[2][8192];   // [buf][hh*512 + dblk*32 + slot][8]
  __shared__ u16 VB[2][8192];   // [buf][hh*512 + keyq*128 + d][8]

  const int h = blockIdx.y, b = blockIdx.z, jb = blockIdx.x;
  const int bh = b * NHc + h;
  const int tid = threadIdx.x;
  const int w = tid >> 6, lane = tid & 63;
  const int l15 = lane & 15, quad = lane >> 4;

  const u16* krb = kr + (size_t)bh * Sc * HDc;
  const u16* vtb = vt + (size_t)bh * HDc * Sc;

  float lp1 = lq1[lane] * lk1[lane];
  float lp2 = lq2[lane] * lk2[lane];
#pragma unroll
  for (int m = 32; m; m >>= 1) { lp1 += __shfl_xor(lp1, m); lp2 += __shfl_xor(lp2, m); }
  const float lam = __expf(lp1) - __expf(lp2) + LAMBDA_INIT_C;

  float wsub[8];
#pragma unroll
  for (int dn = 0; dn < 8; dn++) wsub[dn] = subw[dn * 16 + l15];

  // staging address precompute
  size_t offK[4], offV[4];
  int dstO[4];
#pragma unroll
  for (int oo = 0; oo < 4; oo++) {
    const int n = w * 256 + oo * 64 + lane;
    const int s = n & 31, dblk = (n >> 5) & 15, sub = n >> 9;
    const int mkey = (s & 3) + ((s >> 2) & 3) * 8 + ((s >> 4) << 2);  // key permutation
    offK[oo] = (size_t)(sub * 32 + mkey) * HDc + dblk * 8;
    offV[oo] = (size_t)(n & 127) * Sc + (sub * 32 + ((n >> 7) & 3) * 8);
    dstO[oo] = n * 8;
  }

  for (int ph = 0; ph < 2; ph++) {
    const int t = ph ? (31 - jb) : jb;
    const int rowbase = t * 64 + w * 16;
    const int nc = t + 1;   // 64-key chunks

    const u16* qp = qr + ((size_t)bh * Sc + rowbase + l15) * HDc + quad * 8;
    s16x8 qa[2][2];
    qa[0][0] = *(const s16x8*)(qp);
    qa[0][1] = *(const s16x8*)(qp + 32);
    qa[1][0] = *(const s16x8*)(qp + 64);
    qa[1][1] = *(const s16x8*)(qp + 96);

    f32x4 o[2][8];
#pragma unroll
    for (int st = 0; st < 2; st++)
#pragma unroll
      for (int dn = 0; dn < 8; dn++) o[st][dn] = (f32x4){0.f, 0.f, 0.f, 0.f};
    float lpart[2] = { 0.f, 0.f };

    __syncthreads();  // protect buffers from previous phase's readers
#pragma unroll
    for (int oo = 0; oo < 4; oo++) cp16(krb + offK[oo], KB[0] + dstO[oo]);
#pragma unroll
    for (int oo = 0; oo < 4; oo++) cp16(vtb + offV[oo], VB[0] + dstO[oo]);

    for (int c = 0; c < nc; c++) {
      __syncthreads();
      if (c + 1 < nc) {
        const int kb1 = (c + 1) * 64;
        u16* Kn = KB[(c + 1) & 1];
        u16* Vn = VB[(c + 1) & 1];
#pragma unroll
        for (int oo = 0; oo < 4; oo++) cp16(krb + (size_t)kb1 * HDc + offK[oo], Kn + dstO[oo]);
#pragma unroll
        for (int oo = 0; oo < 4; oo++) cp16(vtb + offV[oo] + kb1, Vn + dstO[oo]);
      }
      const u16* Kb = KB[c & 1];
      const u16* Vb = VB[c & 1];
      const int kb = c * 64;
      const bool diag = (c == nc - 1);

#pragma unroll
      for (int sub = 0; sub < 2; sub++) {
        if (diag && sub == 1 && w < 2) continue;  // fully-masked sub, wave-uniform skip

        // QK^T transposed: A=K (permuted rows), B=Q
        f32x4 sc[2][2];
#pragma unroll
        for (int st = 0; st < 2; st++)
#pragma unroll
          for (int kt = 0; kt < 2; kt++) sc[st][kt] = (f32x4){0.f, 0.f, 0.f, 0.f};
#pragma unroll
        for (int st = 0; st < 2; st++)
#pragma unroll
          for (int kh = 0; kh < 2; kh++) {
            const int base = sub * 512 + (st * 8 + kh * 4 + quad) * 32;
#pragma unroll
            for (int kt = 0; kt < 2; kt++) {
              const s16x8 kf = *(const s16x8*)(Kb + (size_t)(base + kt * 16 + l15) * 8);
              sc[st][kt] = mfma16(kf, qa[st][kh], sc[st][kt]);
            }
          }

        // in-lane exp + mask + partial-l + pack (keys at this lane = quad*8+j)
        s16x8 pa[2];
#pragma unroll
        for (int st = 0; st < 2; st++) {
          float p[8];
#pragma unroll
          for (int kt = 0; kt < 2; kt++)
#pragma unroll
            for (int r = 0; r < 4; r++) p[kt * 4 + r] = __expf(sc[st][kt][r]);
          if (diag) {
            const int qrow = rowbase + l15;
            const int kb0 = kb + sub * 32 + quad * 8;
#pragma unroll
            for (int j8 = 0; j8 < 8; j8++)
              if (kb0 + j8 > qrow) p[j8] = 0.f;
          }
          float sm = 0.f;
#pragma unroll
          for (int j8 = 0; j8 < 8; j8++) sm += p[j8];
          lpart[st] += sm;
          union { u16 us[8]; s16x8 vv; } pk;
#pragma unroll
          for (int j8 = 0; j8 < 8; j8++) pk.us[j8] = f2bf(p[j8]);
          pa[st] = pk.vv;
        }

        // PV
#pragma unroll
        for (int dn = 0; dn < 8; dn++) {
          const s16x8 vf =
              *(const s16x8*)(Vb + (size_t)(sub * 512 + quad * 128 + dn * 16 + l15) * 8);
          o[0][dn] = mfma16(pa[0], vf, o[0][dn]);
          o[1][dn] = mfma16(pa[1], vf, o[1][dn]);
        }
      }
    }

    // epilogue: reduce l partials, combine streams, RMSNorm(128), *0.8, write
    float lL0 = lpart[0], lL1 = lpart[1];
    lL0 += __shfl_xor(lL0, 16); lL0 += __shfl_xor(lL0, 32);
    lL1 += __shfl_xor(lL1, 16); lL1 += __shfl_xor(lL1, 32);
    const float inv1 = 1.f / lL0;
    const float inv2 = lam / lL1;
    float i1C[4], i2C[4];
#pragma unroll
    for (int r = 0; r < 4; r++) {
      i1C[r] = __shfl(inv1, quad * 4 + r, 16);
      i2C[r] = __shfl(inv2, quad * 4 + r, 16);
    }
    float yv[8][4], ss[4] = { 0.f, 0.f, 0.f, 0.f };
#pragma unroll
    for (int dn = 0; dn < 8; dn++)
#pragma unroll
      for (int r = 0; r < 4; r++) {
        const float y = o[0][dn][r] * i1C[r] - o[1][dn][r] * i2C[r];
        yv[dn][r] = y;
        ss[r] += y * y;
      }
#pragma unroll
    for (int r = 0; r < 4; r++) {
#pragma unroll
      for (int mm = 1; mm < 16; mm <<= 1) ss[r] += __shfl_xor(ss[r], mm);
    }
    float scl[4];
#pragma unroll
    for (int r = 0; r < 4; r++) scl[r] = rsqrtf(ss[r] * (1.f / 128.f) + 1e-5f) * 0.8f;

    u16* yrow = Y + ((size_t)(b * Sc + h * 128 + t * 4 + w)) * 2048;
#pragma unroll
    for (int dn = 0; dn < 8; dn++)
#pragma unroll
      for (int r = 0; r < 4; r++)
        yrow[(quad * 4 + r) * 128 + dn * 16 + l15] = f2bf(yv[dn][r] * scl[r] * wsub[dn]);
  }
}

// ---------------- host launcher ----------------
extern "C" void kernel_launch(void* const* d_in, const int* in_sizes, int n_in,
                              void* d_out, int out_size, void* d_ws, size_t ws_size,
                              hipStream_t stream) {
  const float* x    = (const float*)d_in[0];
  const float* fc   = (const float*)d_in[1];
  const float* wq   = (const float*)d_in[2];
  const float* wk   = (const float*)d_in[3];
  const float* wv   = (const float*)d_in[4];
  const float* wo   = (const float*)d_in[5];
  const float* lq1  = (const float*)d_in[6];
  const float* lk1  = (const float*)d_in[7];
  const float* lq2  = (const float*)d_in[8];
  const float* lk2  = (const float*)d_in[9];
  const float* subw = (const float*)d_in[10];
  float* out = (float*)d_out;

  char* ws = (char*)d_ws;
  constexpr size_t SZ_X  = (size_t)Tc * DIMc * 2;        // 16 MB
  constexpr size_t SZ_W  = (size_t)DIMc * DIMc * 2;      // 8 MB
  constexpr size_t SZ_T  = (size_t)Tc * DIMc * 2;        // 16 MB
  u16* xb  = (u16*)(ws);
  u16* wqb = (u16*)(ws + SZ_X);                          // wq,wk,wv,wo contiguous
  u16* wob = (u16*)(ws + SZ_X + 3 * SZ_W);
  u16* qg  = (u16*)(ws + SZ_X + 4 * SZ_W);               // qg,kg,vg contiguous
  u16* kg  = (u16*)(ws + SZ_X + 4 * SZ_W + SZ_T);
  u16* vg  = (u16*)(ws + SZ_X + 4 * SZ_W + 2 * SZ_T);
  u16* qr  = (u16*)(ws + SZ_X + 4 * SZ_W + 3 * SZ_T);
  u16* kr  = (u16*)(ws + SZ_X + 4 * SZ_W + 4 * SZ_T);
  u16* vt  = (u16*)(ws + SZ_X + 4 * SZ_W + 5 * SZ_T);
  u16* Y   = (u16*)(ws + SZ_X + 4 * SZ_W + 6 * SZ_T);

  // 1) fp32 -> bf16 (one dispatch: x + 4 weights)
  cvt_all_kernel<<<(Tc * DIMc / 4 + 4 * DIMc * DIMc / 4) / 256, 256, 0, stream>>>(
      x, wq, wk, wv, wo, xb, wqb);

  // 2) merged QKV projection GEMM: A=xb [4096][2048], B=wqb.. [6144][2048]
  //    grid 24x16 = 384 blocks (256x256 tiles)
  gemm8p<0, 256><<<dim3(DIMc * 3 / 256, Tc / 256), 512, 0, stream>>>(
      xb, wqb, qg, nullptr);

  // 3) fused prep: rope(q, *0.125) + rope(k) + vtrans (one dispatch)
  prep_kernel<<<16384 + 16384 + 8192, 256, 0, stream>>>(qg, kg, vg, fc, qr, kr, vt);

  // 4) fused causal differential attention -> permuted Y
  diff_attn_kernel<<<dim3(16, NHc, Bc), 256, 0, stream>>>(
      qr, kr, vt, lq1, lk1, lq2, lk2, subw, Y);

  // 5) output GEMM (fp32 out): 128x256 tiles -> grid 8x32 = 256 blocks = 1/CU
  gemm8p<1, 128><<<dim3(DIMc / 256, Tc / 128), 512, 0, stream>>>(
      Y, wob, nullptr, out);
}

// Round 4
// 410.053 us; speedup vs baseline: 1.0713x; 1.0165x over previous
//
#include <hip/hip_runtime.h>

typedef unsigned short u16;
typedef unsigned int   u32;
typedef __attribute__((ext_vector_type(8))) short s16x8;
typedef __attribute__((ext_vector_type(4))) float f32x4;

constexpr int Bc = 2, Sc = 2048, DIMc = 2048, NHc = 16, HDc = 128, Tc = Bc * Sc;
constexpr float LAMBDA_INIT_C = 0.2f;   // 0.8 - 0.6*exp(0)

__device__ __forceinline__ u16 f2bf(float f) {
  union { float f; u32 u; } v; v.f = f;
  u32 r = v.u + 0x7fffu + ((v.u >> 16) & 1u);   // RNE
  return (u16)(r >> 16);
}
__device__ __forceinline__ float bf2f(u16 b) {
  union { u32 u; float f; } v; v.u = ((u32)b) << 16;
  return v.f;
}
__device__ __forceinline__ f32x4 mfma16(s16x8 a, s16x8 b, f32x4 c) {
  return __builtin_amdgcn_mfma_f32_16x16x32_bf16(a, b, c, 0, 0, 0);
}

typedef const __attribute__((address_space(1))) u32 gq32;
typedef __attribute__((address_space(3))) u32 lq32;
__device__ __forceinline__ void cp16(const u16* g, u16* l) {
  __builtin_amdgcn_global_load_lds((gq32*)g, (lq32*)l, 16, 0, 0);
}

#define BAR()    asm volatile("s_barrier" ::: "memory")
#define LGKM(n)  asm volatile("s_waitcnt lgkmcnt(" #n ")" ::: "memory")
#define VMC(n)   asm volatile("s_waitcnt vmcnt(" #n ")" ::: "memory")
#define SCHED0() __builtin_amdgcn_sched_barrier(0)

// ---------------- fp32 -> bf16 convert: x + 4 contiguous weight tensors --------
__global__ void cvt_all_kernel(const float* __restrict__ x,
                               const float* __restrict__ wq, const float* __restrict__ wk,
                               const float* __restrict__ wv, const float* __restrict__ wo,
                               u16* __restrict__ xb, u16* __restrict__ wb) {
  const int i = blockIdx.x * 256 + threadIdx.x;
  constexpr int NX = Tc * DIMc / 4;       // 2^21 float4
  constexpr int PW = DIMc * DIMc / 4;     // 2^20 float4 per weight
  float4 v; uint2* dst;
  if (i < NX) {
    v = ((const float4*)x)[i];
    dst = ((uint2*)xb) + i;
  } else {
    const int j = i - NX;
    const int which = j >> 20;
    const int jj = j & (PW - 1);
    const float* src = which == 0 ? wq : which == 1 ? wk : which == 2 ? wv : wo;
    v = ((const float4*)src)[jj];
    dst = ((uint2*)wb) + j;
  }
  union { u16 u[4]; uint2 p; } o;
  o.u[0] = f2bf(v.x); o.u[1] = f2bf(v.y); o.u[2] = f2bf(v.z); o.u[3] = f2bf(v.w);
  *dst = o.p;
}

// ============ 128x256x64 free-running GEMM (seam-barrier schedule) ===========
// C[m][n] = sum_k A[m][k]*B[n][k]; A:[M][2048], B:[N][2048] bf16 row-major.
// MODE 0: bf16 out, N=6144 routed to 3 [4096][2048] outputs (QKV). grid 24x32
//         = 768 blocks = exactly 3/CU (balanced makespan).
// MODE 1: fp32 out, N=2048. grid 8x32 = 256 blocks = exactly 1/CU.
//
// 512 thr = 8 waves (2M x 4N), wave tile 64x64, acc[4][4] f32x4.
// LDS 96 KiB = 2 bufs x (A 128x64 + B 256x64) bf16, XOR-swizzle 16B-slot ^=
// row&7 (pre-swizzled global src + swizzled ds_read; linear gload_lds dest).
//
// KEY CHANGE vs prior rounds: waves FREE-RUN inside a K-tile (no per-phase
// barriers). Lockstep phases made all waves read LDS together then MFMA
// together -- LDS and MFMA pipes alternated idle, capping MfmaUtil at ~33%.
// Now per wave per K-tile:
//   read k0 frags (8), read k1 frags (8, alt regs), stage A(kt+1)->nb;
//   lgkmcnt(8)  -> k0 resident;  MFMA 16 (k0)   [k1 reads still in flight]
//   lgkmcnt(0)  -> k1 resident;  MFMA 16 (k1)
//   BAR1; stB(kt+2)->cb; vmcnt(4); BAR2          (the only 2 barriers)
// Cross-wave overlap: one wave's MFMA covers another's LDS reads.
//
// Hazard ledger:
//  - BAR1: all waves have drained their cb reads (lgkmcnt(0) precedes their
//    MFMA-k1 which precedes BAR1) => stB into cb.B is safe; stA(kt+1)->nb at
//    next-tile P0 is safe because nb.A's last reads drained before the
//    PREVIOUS seam's BAR1.
//  - vmcnt(4) at seam: per-wave staging ops in issue order are
//    ...stB(kt+1)[4]@(kt-1).seam, stA(kt+1)[2]@kt.P0, stB(kt+2)[4]@kt.seam.
//    <=4 outstanding => stA(kt+1) and stB(kt+1) complete. BAR2 broadcasts
//    this across waves => kt+1 reads are safe. Never drains to 0 in-loop.
//  - Tail: wrapped kt=0 dummies into regions never read again.
template<int MODE>
__global__ __launch_bounds__(512, 2) void gemm8p(const u16* __restrict__ A,
                                                 const u16* __restrict__ Bw,
                                                 u16* __restrict__ Cb,
                                                 float* __restrict__ Cf) {
  constexpr int K = 2048, NT = K / 64;
  constexpr int AU  = 128 * 64;          // 8192 u16
  constexpr int BUF = AU + 16384;        // 24576 u16 = 48 KiB per buffer
  __shared__ __align__(16) u16 L[2 * BUF];

  const int tid  = threadIdx.x;
  const int lane = tid & 63, w = tid >> 6;
  const int wm = w >> 2, wn = w & 3;
  const int l15 = lane & 15, quad = lane >> 4;

  // XCD swizzle (n-major flat: each XCD gets contiguous N-columns).
  const int mt   = gridDim.y;
  const int nwg  = gridDim.x * mt;
  const int flat = blockIdx.x * mt + blockIdx.y;
  const int swz  = (flat & 7) * (nwg >> 3) + (flat >> 3);
  const int nbase = (swz / mt) * 256;
  const int mbase = (swz % mt) * 128;

  const u16* Ag = A  + (size_t)mbase * K;
  const u16* Bg = Bw + (size_t)nbase * K;

  // staging: 16B-granule n = l*512+tid; row r=n>>3, LDS slot s=n&7 holds
  // logical k-granule q = s^(r&7)  (inverse-swizzled global source).
  u32 soffA[2], dlinA[2], soffB[4], dlinB[4];
#pragma unroll
  for (int l = 0; l < 2; l++) {
    const int n = l * 512 + tid;
    const int r = n >> 3;
    const u32 q = (u32)((n & 7) ^ (r & 7));
    soffA[l] = (u32)r * K + q * 8;
    dlinA[l] = (u32)n * 8;
  }
#pragma unroll
  for (int l = 0; l < 4; l++) {
    const int n = l * 512 + tid;
    const int r = n >> 3;
    const u32 q = (u32)((n & 7) ^ (r & 7));
    soffB[l] = (u32)r * K + q * 8;
    dlinB[l] = (u32)(AU + n * 8);
  }

  auto stA = [&](int kt, int bb) {
#pragma unroll
    for (int l = 0; l < 2; l++)
      cp16(Ag + (size_t)kt * 64 + soffA[l], L + bb + dlinA[l]);
  };
  auto stB = [&](int kt, int bb) {
#pragma unroll
    for (int l = 0; l < 4; l++)
      cp16(Bg + (size_t)kt * 64 + soffB[l], L + bb + dlinB[l]);
  };

  // ds_read bases; swizzled slot (q ^ (row&7))<<3, row&7 == l15&7
  const int aB  = (wm * 64 + l15) * 64;
  const int bB  = AU + (wn * 64 + l15) * 64;
  const int xq0 = (quad ^ (l15 & 7)) << 3;   // kk=0; kk=1 slot = xq0 ^ 32

  f32x4 acc[4][4];
#pragma unroll
  for (int i = 0; i < 4; i++)
#pragma unroll
    for (int j = 0; j < 4; j++) acc[i][j] = (f32x4){0.f, 0.f, 0.f, 0.f};

  // prologue: B0,A0 -> buf0; B1 -> buf1. vmcnt(4): B0(4)+A0(2)+B1(4)=10 ops,
  // <=4 outstanding => B0,A0 done; B1 (<=4) may remain in flight.
  stB(0, 0); stA(0, 0); stB(1, BUF);
  VMC(4);
  BAR();

  s16x8 a0[4], b0[4], a1[4], b1[4];

  for (int kt = 0; kt < NT; ++kt) {
    const int cb = (kt & 1) * BUF;
    const int nb = BUF - cb;
    const int tgA = (kt + 1 < NT) ? kt + 1 : 0;   // wrapped dummy in tail
    const int tgB = (kt + 2 < NT) ? kt + 2 : 0;

    // ---- issue ALL reads for this K-tile (k0 then k1), + stage A(kt+1)
#pragma unroll
    for (int j = 0; j < 4; j++)
      b0[j] = *(const s16x8*)(L + cb + bB + j * 1024 + xq0);
#pragma unroll
    for (int i = 0; i < 4; i++)
      a0[i] = *(const s16x8*)(L + cb + aB + i * 1024 + xq0);
#pragma unroll
    for (int j = 0; j < 4; j++)
      b1[j] = *(const s16x8*)(L + cb + bB + j * 1024 + (xq0 ^ 32));
#pragma unroll
    for (int i = 0; i < 4; i++)
      a1[i] = *(const s16x8*)(L + cb + aB + i * 1024 + (xq0 ^ 32));
    stA(tgA, nb);

    // ---- k0 compute: wait only the first 8 reads (counted lgkm)
    LGKM(8); SCHED0();
    __builtin_amdgcn_s_setprio(1);
#pragma unroll
    for (int i = 0; i < 4; i++)
#pragma unroll
      for (int j = 0; j < 4; j++) acc[i][j] = mfma16(a0[i], b0[j], acc[i][j]);
    __builtin_amdgcn_s_setprio(0);

    // ---- k1 compute
    LGKM(0); SCHED0();
    __builtin_amdgcn_s_setprio(1);
#pragma unroll
    for (int i = 0; i < 4; i++)
#pragma unroll
      for (int j = 0; j < 4; j++) acc[i][j] = mfma16(a1[i], b1[j], acc[i][j]);
    __builtin_amdgcn_s_setprio(0);

    // ---- seam: the only barriers
    BAR();                 // all waves drained cb reads -> cb.B stage safe
    stB(tgB, cb);
    VMC(4);                // A(kt+1), B(kt+1) complete (see ledger)
    BAR();                 // broadcast completion -> kt+1 reads safe
  }
  asm volatile("s_waitcnt vmcnt(0)" ::: "memory");   // drain tail dummies

  // ---- epilogue: C write (C/D layout: row = quad*4+r, col = l15)
  if (MODE == 0) {
    const int which = nbase >> 11;
    const int ncol  = nbase & 2047;
    u16* Ob = Cb + (size_t)which * ((size_t)Tc * DIMc);
#pragma unroll
    for (int i = 0; i < 4; i++) {
      const int m0 = mbase + wm * 64 + i * 16 + quad * 4;
#pragma unroll
      for (int j = 0; j < 4; j++) {
        const int n0 = ncol + wn * 64 + j * 16 + l15;
#pragma unroll
        for (int r = 0; r < 4; r++)
          Ob[(size_t)(m0 + r) * 2048 + n0] = f2bf(acc[i][j][r]);
      }
    }
  } else {
#pragma unroll
    for (int i = 0; i < 4; i++) {
      const int m0 = mbase + wm * 64 + i * 16 + quad * 4;
#pragma unroll
      for (int j = 0; j < 4; j++) {
        const int n0 = nbase + wn * 64 + j * 16 + l15;
#pragma unroll
        for (int r = 0; r < 4; r++)
          Cf[(size_t)(m0 + r) * 2048 + n0] = acc[i][j][r];
      }
    }
  }
}

// ---------------- fused prep: rope(q), rope(k), vtrans in one dispatch ----------
__global__ void prep_kernel(const u16* __restrict__ qg, const u16* __restrict__ kg,
                            const u16* __restrict__ vg, const float* __restrict__ fc,
                            u16* __restrict__ qr, u16* __restrict__ kr,
                            u16* __restrict__ vt) {
  __shared__ u16 tile[32][33];
  const int bid = blockIdx.x;
  if (bid < 32768) {
    const bool isq = bid < 16384;
    const u16* xg = isq ? qg : kg;
    u16* outp = isq ? qr : kr;
    const float scale = isq ? 0.125f : 1.0f;  // Q pre-scaled by 1/sqrt(64)
    const int idx = (bid & 16383) * 256 + threadIdx.x;
    const int p = idx & 63;
    const int hh = (idx >> 6) & 15;
    const int tt = idx >> 10;
    const int s = tt & (Sc - 1);
    const int bb = tt >> 11;
    const float c  = fc[(size_t)(s * 64 + p) * 4 + 0] * scale;  // cos
    const float sn = fc[(size_t)(s * 64 + p) * 4 + 2] * scale;  // sin
    const u32 xp = *(const u32*)(xg + (size_t)tt * DIMc + hh * HDc + p * 2);
    const float x0 = bf2f((u16)xp), x1 = bf2f((u16)(xp >> 16));
    const u16 y0 = f2bf(c * x0 - sn * x1);
    const u16 y1 = f2bf(sn * x0 + c * x1);
    *(u32*)(outp + ((size_t)(bb * NHc + hh) * Sc + s) * HDc + p * 2) =
        (u32)y0 | ((u32)y1 << 16);
  } else {
    const int vb = bid - 32768;
    const int bh = vb >> 8;
    const int bb = bh >> 4, hh = bh & 15;
    const int rem = vb & 255;
    const int s0 = (rem & 63) * 32, d0 = (rem >> 6) * 32;
    const int tx = threadIdx.x & 31, ty = threadIdx.x >> 5;
#pragma unroll
    for (int pp = 0; pp < 4; pp++) {
      const int s = s0 + ty + pp * 8;
      tile[ty + pp * 8][tx] = vg[(size_t)(bb * Sc + s) * DIMc + hh * HDc + d0 + tx];
    }
    __syncthreads();
#pragma unroll
    for (int pp = 0; pp < 4; pp++) {
      const int d = d0 + ty + pp * 8;
      vt[((size_t)bh * HDc + d) * Sc + s0 + tx] = tile[tx][ty + pp * 8];
    }
  }
}

// ---------------- fused causal diff-attention -> permuted Y ----------------
// Balanced pairing: block j handles 64-row q-tiles j and 31-j; 64-key chunks
// (two independent 32-key subs per barrier). K rows are PERMUTED at staging
// (per-lane global source addr; LDS dest stays linear) with
// m(s) = (s&3) + ((s>>2)&3)*8 + ((s>>4)<<2), and QK^T is computed transposed
// (A=K, B=Q) so the score C-layout keys at lane (quad,l15) are exactly keys
// quad*8+j -- identical to the PV A-fragment layout and VB's key order. The
// score transpose through LDS disappears; P packs in-register after exp.
__global__ __launch_bounds__(256, 2) void diff_attn_kernel(
    const u16* __restrict__ qr, const u16* __restrict__ kr, const u16* __restrict__ vt,
    const float* __restrict__ lq1, const float* __restrict__ lk1,
    const float* __restrict__ lq2, const float* __restrict__ lk2,
    const float* __restrict__ subw, u16* __restrict__ Y) {
  __shared__ u16 KB[2][8192];   // [buf][hh*512 + dblk*32 + slot][8]
  __shared__ u16 VB[2][8192];   // [buf][hh*512 + keyq*128 + d][8]

  const int h = blockIdx.y, b = blockIdx.z, jb = blockIdx.x;
  const int bh = b * NHc + h;
  const int tid = threadIdx.x;
  const int w = tid >> 6, lane = tid & 63;
  const int l15 = lane & 15, quad = lane >> 4;

  const u16* krb = kr + (size_t)bh * Sc * HDc;
  const u16* vtb = vt + (size_t)bh * HDc * Sc;

  float lp1 = lq1[lane] * lk1[lane];
  float lp2 = lq2[lane] * lk2[lane];
#pragma unroll
  for (int m = 32; m; m >>= 1) { lp1 += __shfl_xor(lp1, m); lp2 += __shfl_xor(lp2, m); }
  const float lam = __expf(lp1) - __expf(lp2) + LAMBDA_INIT_C;

  float wsub[8];
#pragma unroll
  for (int dn = 0; dn < 8; dn++) wsub[dn] = subw[dn * 16 + l15];

  // staging address precompute
  size_t offK[4], offV[4];
  int dstO[4];
#pragma unroll
  for (int oo = 0; oo < 4; oo++) {
    const int n = w * 256 + oo * 64 + lane;
    const int s = n & 31, dblk = (n >> 5) & 15, sub = n >> 9;
    const int mkey = (s & 3) + ((s >> 2) & 3) * 8 + ((s >> 4) << 2);  // key permutation
    offK[oo] = (size_t)(sub * 32 + mkey) * HDc + dblk * 8;
    offV[oo] = (size_t)(n & 127) * Sc + (sub * 32 + ((n >> 7) & 3) * 8);
    dstO[oo] = n * 8;
  }

  for (int ph = 0; ph < 2; ph++) {
    const int t = ph ? (31 - jb) : jb;
    const int rowbase = t * 64 + w * 16;
    const int nc = t + 1;   // 64-key chunks

    const u16* qp = qr + ((size_t)bh * Sc + rowbase + l15) * HDc + quad * 8;
    s16x8 qa[2][2];
    qa[0][0] = *(const s16x8*)(qp);
    qa[0][1] = *(const s16x8*)(qp + 32);
    qa[1][0] = *(const s16x8*)(qp + 64);
    qa[1][1] = *(const s16x8*)(qp + 96);

    f32x4 o[2][8];
#pragma unroll
    for (int st = 0; st < 2; st++)
#pragma unroll
      for (int dn = 0; dn < 8; dn++) o[st][dn] = (f32x4){0.f, 0.f, 0.f, 0.f};
    float lpart[2] = { 0.f, 0.f };

    __syncthreads();  // protect buffers from previous phase's readers
#pragma unroll
    for (int oo = 0; oo < 4; oo++) cp16(krb + offK[oo], KB[0] + dstO[oo]);
#pragma unroll
    for (int oo = 0; oo < 4; oo++) cp16(vtb + offV[oo], VB[0] + dstO[oo]);

    for (int c = 0; c < nc; c++) {
      __syncthreads();
      if (c + 1 < nc) {
        const int kb1 = (c + 1) * 64;
        u16* Kn = KB[(c + 1) & 1];
        u16* Vn = VB[(c + 1) & 1];
#pragma unroll
        for (int oo = 0; oo < 4; oo++) cp16(krb + (size_t)kb1 * HDc + offK[oo], Kn + dstO[oo]);
#pragma unroll
        for (int oo = 0; oo < 4; oo++) cp16(vtb + offV[oo] + kb1, Vn + dstO[oo]);
      }
      const u16* Kb = KB[c & 1];
      const u16* Vb = VB[c & 1];
      const int kb = c * 64;
      const bool diag = (c == nc - 1);

#pragma unroll
      for (int sub = 0; sub < 2; sub++) {
        if (diag && sub == 1 && w < 2) continue;  // fully-masked sub, wave-uniform skip

        // QK^T transposed: A=K (permuted rows), B=Q
        f32x4 sc[2][2];
#pragma unroll
        for (int st = 0; st < 2; st++)
#pragma unroll
          for (int kt = 0; kt < 2; kt++) sc[st][kt] = (f32x4){0.f, 0.f, 0.f, 0.f};
#pragma unroll
        for (int st = 0; st < 2; st++)
#pragma unroll
          for (int kh = 0; kh < 2; kh++) {
            const int base = sub * 512 + (st * 8 + kh * 4 + quad) * 32;
#pragma unroll
            for (int kt = 0; kt < 2; kt++) {
              const s16x8 kf = *(const s16x8*)(Kb + (size_t)(base + kt * 16 + l15) * 8);
              sc[st][kt] = mfma16(kf, qa[st][kh], sc[st][kt]);
            }
          }

        // in-lane exp + mask + partial-l + pack (keys at this lane = quad*8+j)
        s16x8 pa[2];
#pragma unroll
        for (int st = 0; st < 2; st++) {
          float p[8];
#pragma unroll
          for (int kt = 0; kt < 2; kt++)
#pragma unroll
            for (int r = 0; r < 4; r++) p[kt * 4 + r] = __expf(sc[st][kt][r]);
          if (diag) {
            const int qrow = rowbase + l15;
            const int kb0 = kb + sub * 32 + quad * 8;
#pragma unroll
            for (int j8 = 0; j8 < 8; j8++)
              if (kb0 + j8 > qrow) p[j8] = 0.f;
          }
          float sm = 0.f;
#pragma unroll
          for (int j8 = 0; j8 < 8; j8++) sm += p[j8];
          lpart[st] += sm;
          union { u16 us[8]; s16x8 vv; } pk;
#pragma unroll
          for (int j8 = 0; j8 < 8; j8++) pk.us[j8] = f2bf(p[j8]);
          pa[st] = pk.vv;
        }

        // PV
#pragma unroll
        for (int dn = 0; dn < 8; dn++) {
          const s16x8 vf =
              *(const s16x8*)(Vb + (size_t)(sub * 512 + quad * 128 + dn * 16 + l15) * 8);
          o[0][dn] = mfma16(pa[0], vf, o[0][dn]);
          o[1][dn] = mfma16(pa[1], vf, o[1][dn]);
        }
      }
    }

    // epilogue: reduce l partials, combine streams, RMSNorm(128), *0.8, write
    float lL0 = lpart[0], lL1 = lpart[1];
    lL0 += __shfl_xor(lL0, 16); lL0 += __shfl_xor(lL0, 32);
    lL1 += __shfl_xor(lL1, 16); lL1 += __shfl_xor(lL1, 32);
    const float inv1 = 1.f / lL0;
    const float inv2 = lam / lL1;
    float i1C[4], i2C[4];
#pragma unroll
    for (int r = 0; r < 4; r++) {
      i1C[r] = __shfl(inv1, quad * 4 + r, 16);
      i2C[r] = __shfl(inv2, quad * 4 + r, 16);
    }
    float yv[8][4], ss[4] = { 0.f, 0.f, 0.f, 0.f };
#pragma unroll
    for (int dn = 0; dn < 8; dn++)
#pragma unroll
      for (int r = 0; r < 4; r++) {
        const float y = o[0][dn][r] * i1C[r] - o[1][dn][r] * i2C[r];
        yv[dn][r] = y;
        ss[r] += y * y;
      }
#pragma unroll
    for (int r = 0; r < 4; r++) {
#pragma unroll
      for (int mm = 1; mm < 16; mm <<= 1) ss[r] += __shfl_xor(ss[r], mm);
    }
    float scl[4];
#pragma unroll
    for (int r = 0; r < 4; r++) scl[r] = rsqrtf(ss[r] * (1.f / 128.f) + 1e-5f) * 0.8f;

    u16* yrow = Y + ((size_t)(b * Sc + h * 128 + t * 4 + w)) * 2048;
#pragma unroll
    for (int dn = 0; dn < 8; dn++)
#pragma unroll
      for (int r = 0; r < 4; r++)
        yrow[(quad * 4 + r) * 128 + dn * 16 + l15] = f2bf(yv[dn][r] * scl[r] * wsub[dn]);
  }
}

// ---------------- host launcher ----------------
extern "C" void kernel_launch(void* const* d_in, const int* in_sizes, int n_in,
                              void* d_out, int out_size, void* d_ws, size_t ws_size,
                              hipStream_t stream) {
  const float* x    = (const float*)d_in[0];
  const float* fc   = (const float*)d_in[1];
  const float* wq   = (const float*)d_in[2];
  const float* wk   = (const float*)d_in[3];
  const float* wv   = (const float*)d_in[4];
  const float* wo   = (const float*)d_in[5];
  const float* lq1  = (const float*)d_in[6];
  const float* lk1  = (const float*)d_in[7];
  const float* lq2  = (const float*)d_in[8];
  const float* lk2  = (const float*)d_in[9];
  const float* subw = (const float*)d_in[10];
  float* out = (float*)d_out;

  char* ws = (char*)d_ws;
  constexpr size_t SZ_X  = (size_t)Tc * DIMc * 2;        // 16 MB
  constexpr size_t SZ_W  = (size_t)DIMc * DIMc * 2;      // 8 MB
  constexpr size_t SZ_T  = (size_t)Tc * DIMc * 2;        // 16 MB
  u16* xb  = (u16*)(ws);
  u16* wqb = (u16*)(ws + SZ_X);                          // wq,wk,wv,wo contiguous
  u16* wob = (u16*)(ws + SZ_X + 3 * SZ_W);
  u16* qg  = (u16*)(ws + SZ_X + 4 * SZ_W);               // qg,kg,vg contiguous
  u16* kg  = (u16*)(ws + SZ_X + 4 * SZ_W + SZ_T);
  u16* vg  = (u16*)(ws + SZ_X + 4 * SZ_W + 2 * SZ_T);
  u16* qr  = (u16*)(ws + SZ_X + 4 * SZ_W + 3 * SZ_T);
  u16* kr  = (u16*)(ws + SZ_X + 4 * SZ_W + 4 * SZ_T);
  u16* vt  = (u16*)(ws + SZ_X + 4 * SZ_W + 5 * SZ_T);
  u16* Y   = (u16*)(ws + SZ_X + 4 * SZ_W + 6 * SZ_T);

  // 1) fp32 -> bf16 (one dispatch: x + 4 weights)
  cvt_all_kernel<<<(Tc * DIMc / 4 + 4 * DIMc * DIMc / 4) / 256, 256, 0, stream>>>(
      x, wq, wk, wv, wo, xb, wqb);

  // 2) merged QKV projection GEMM: A=xb [4096][2048], B=wqb.. [6144][2048]
  //    grid 24x32 = 768 blocks = exactly 3 per CU
  gemm8p<0><<<dim3(DIMc * 3 / 256, Tc / 128), 512, 0, stream>>>(
      xb, wqb, qg, nullptr);

  // 3) fused prep: rope(q, *0.125) + rope(k) + vtrans (one dispatch)
  prep_kernel<<<16384 + 16384 + 8192, 256, 0, stream>>>(qg, kg, vg, fc, qr, kr, vt);

  // 4) fused causal differential attention -> permuted Y
  diff_attn_kernel<<<dim3(16, NHc, Bc), 256, 0, stream>>>(
      qr, kr, vt, lq1, lk1, lq2, lk2, subw, Y);

  // 5) output GEMM (fp32 out): grid 8x32 = 256 blocks = exactly 1 per CU
  gemm8p<1><<<dim3(DIMc / 256, Tc / 128), 512, 0, stream>>>(
      Y, wob, nullptr, out);
}